// Round 3
// baseline (360.756 us; speedup 1.0000x reference)
//
#include <hip/hip_runtime.h>

#define NN 50000
#define NE 800000
#define H  64

typedef __attribute__((ext_vector_type(8))) short bf16x8;
typedef __attribute__((ext_vector_type(4))) float f32x4;

__device__ __forceinline__ unsigned short f2bf(float f) {
  unsigned int u = __builtin_bit_cast(unsigned int, f);
  u += 0x7FFFu + ((u >> 16) & 1u);  // RNE
  return (unsigned short)(u >> 16);
}
__device__ __forceinline__ float bf2f(unsigned short u) {
  unsigned int v = ((unsigned int)u) << 16;
  return __builtin_bit_cast(float, v);
}

// ---------- count in-degree (dst) ----------
__global__ __launch_bounds__(256) void k_zero(int* __restrict__ cnt) {
  int i = blockIdx.x * 256 + threadIdx.x;
  if (i < NN) cnt[i] = 0;
}

__global__ __launch_bounds__(256) void k_hist(const int* __restrict__ ei,
                                              int* __restrict__ cnt) {
  int e = blockIdx.x * 256 + threadIdx.x;
  atomicAdd(&cnt[ei[NE + e]], 1);
}

// ---------- exclusive scan over 50k counts; rowptr/cursor/dinv ----------
__global__ __launch_bounds__(1024) void k_scan(const int* __restrict__ cnt,
                                               int* __restrict__ rowptr,
                                               int* __restrict__ cursor,
                                               float* __restrict__ dinv) {
  __shared__ int part[1024];
  const int t = threadIdx.x;
  const int base = t * 49;  // 1024*49 = 50176 >= NN
  int s = 0;
#pragma unroll 1
  for (int j = 0; j < 49; ++j) {
    int idx = base + j;
    s += (idx < NN) ? cnt[idx] : 0;
  }
  int val = s;
  part[t] = val;
  __syncthreads();
#pragma unroll 1
  for (int off = 1; off < 1024; off <<= 1) {
    int other = (t >= off) ? part[t - off] : 0;
    __syncthreads();
    val += other;
    part[t] = val;
    __syncthreads();
  }
  int running = val - s;  // exclusive offset for this thread's chunk
#pragma unroll 1
  for (int j = 0; j < 49; ++j) {
    int idx = base + j;
    if (idx < NN) {
      int c = cnt[idx];
      rowptr[idx] = running;
      cursor[idx] = running;
      dinv[idx] = rsqrtf((float)(c + 1));  // +1 self-loop
      running += c;
    }
  }
  if (t == 0) rowptr[NN] = part[1023];
}

// ---------- node encoder + h0@W_gcn; htb = bf16(ht * dinv[n]) ----------
__global__ __launch_bounds__(256) void k_node(
    const float* __restrict__ x, const float* __restrict__ W_ne,
    const float* __restrict__ b_ne, const float* __restrict__ W_gcn,
    const float* __restrict__ dinv, unsigned short* __restrict__ htb) {
  __shared__ float sh[4][H];
  const int lane = threadIdx.x & 63;
  const int wv   = threadIdx.x >> 6;
  const int n    = blockIdx.x * 4 + wv;

  float acc = b_ne[lane];
#pragma unroll
  for (int k = 0; k < 5; ++k) acc = fmaf(x[n * 5 + k], W_ne[k * H + lane], acc);
  acc = fmaxf(acc, 0.0f);
  sh[wv][lane] = acc;
  __syncthreads();

  float hv = 0.0f;
#pragma unroll 8
  for (int k = 0; k < H; ++k) hv = fmaf(sh[wv][k], W_gcn[k * H + lane], hv);

  htb[(size_t)n * H + lane] = f2bf(hv * dinv[n]);
}

// ---------- reorder: csr_src grouped by dst ----------
__global__ __launch_bounds__(256) void k_reorder(const int* __restrict__ ei,
                                                 int* __restrict__ cursor,
                                                 int* __restrict__ csr_src) {
  int e = blockIdx.x * 256 + threadIdx.x;
  int s = ei[e], d = ei[NE + e];
  int pos = atomicAdd(&cursor[d], 1);
  csr_src[pos] = s;
}

// ---------- gather: hgb[d] = bf16(dinv[d]*(htb[d] + sum htb[src]) + b_gcn) ----------
__global__ __launch_bounds__(256) void k_gather(
    const int* __restrict__ rowptr, const int* __restrict__ csr_src,
    const unsigned short* __restrict__ htb, const float* __restrict__ dinv,
    const float* __restrict__ b_gcn, unsigned short* __restrict__ hgb) {
  const int lane = threadIdx.x & 63;
  const int wv   = threadIdx.x >> 6;
  const int n    = blockIdx.x * 4 + wv;  // NN % 4 == 0
  const int beg = rowptr[n], end = rowptr[n + 1];

  float sum = bf2f(htb[(size_t)n * H + lane]);  // self-loop term
  int i = beg;
#pragma unroll 1
  for (; i + 4 <= end; i += 4) {
    const int s0 = csr_src[i], s1 = csr_src[i + 1];
    const int s2 = csr_src[i + 2], s3 = csr_src[i + 3];
    const float v0 = bf2f(htb[(size_t)s0 * H + lane]);
    const float v1 = bf2f(htb[(size_t)s1 * H + lane]);
    const float v2 = bf2f(htb[(size_t)s2 * H + lane]);
    const float v3 = bf2f(htb[(size_t)s3 * H + lane]);
    sum += (v0 + v1) + (v2 + v3);
  }
#pragma unroll 1
  for (; i < end; ++i) sum += bf2f(htb[(size_t)csr_src[i] * H + lane]);

  hgb[(size_t)n * H + lane] = f2bf(fmaf(dinv[n], sum, b_gcn[lane]));
}

// ---------- prep: W1 (f32 [192][64]) -> W1t (bf16 [64][200], padded) ----------
__global__ __launch_bounds__(256) void k_prep_w1t(const float* __restrict__ W1,
                                                  unsigned short* __restrict__ W1t) {
  const int t = blockIdx.x * 256 + threadIdx.x;  // 48*256 = 12288 = 192*64
  const int n = t / 192, k = t % 192;
  W1t[n * 200 + k] = f2bf(W1[k * H + n]);
}

// ---------- MFMA edge MLP ----------
__global__ __launch_bounds__(256) void k_mlp_mfma(
    const int* __restrict__ ei, const float* __restrict__ eattr,
    const unsigned short* __restrict__ hgb, const unsigned short* __restrict__ W1t,
    const float* __restrict__ W_ee, const float* __restrict__ b_ee,
    const float* __restrict__ b1, const float* __restrict__ W2,
    const float* __restrict__ b2, float* __restrict__ out) {
  __shared__ unsigned short sB[64 * 200];  // 25.6 KB, [n][k] padded

  {  // cooperative LDS fill: 12800 ushort = 6400 dwords = 25/thread
    const unsigned int* g = (const unsigned int*)W1t;
    unsigned int* s = (unsigned int*)sB;
#pragma unroll
    for (int i = 0; i < 25; ++i) s[threadIdx.x + 256 * i] = g[threadIdx.x + 256 * i];
  }
  __syncthreads();

  const int lane = threadIdx.x & 63;
  const int wv   = threadIdx.x >> 6;
  const int l15  = lane & 15;
  const int l4   = lane >> 4;

  float wee[16], bee[16], w2v[4], b1v[4];
#pragma unroll
  for (int j = 0; j < 8; ++j) {
    wee[j]     = W_ee[l4 * 8 + j];      bee[j]     = b_ee[l4 * 8 + j];
    wee[8 + j] = W_ee[32 + l4 * 8 + j]; bee[8 + j] = b_ee[32 + l4 * 8 + j];
  }
#pragma unroll
  for (int nt = 0; nt < 4; ++nt) {
    w2v[nt] = W2[l15 + 16 * nt];
    b1v[nt] = b1[l15 + 16 * nt];
  }
  const float bias2 = b2[0];

#pragma unroll 1
  for (int t = 0; t < 4; ++t) {
    const int eBase = (blockIdx.x * 16 + wv * 4 + t) * 16;
    const int el = eBase + l15;
    const int s = ei[el], d = ei[NE + el];
    const float ea = eattr[el];

    const bf16x8 a_s0 = *(const bf16x8*)(hgb + (size_t)s * H + l4 * 8);
    const bf16x8 a_s1 = *(const bf16x8*)(hgb + (size_t)s * H + 32 + l4 * 8);
    const bf16x8 a_d0 = *(const bf16x8*)(hgb + (size_t)d * H + l4 * 8);
    const bf16x8 a_d1 = *(const bf16x8*)(hgb + (size_t)d * H + 32 + l4 * 8);

    bf16x8 ae0, ae1;
#pragma unroll
    for (int j = 0; j < 8; ++j) {
      ae0[j] = (short)f2bf(fmaxf(fmaf(ea, wee[j], bee[j]), 0.0f));
      ae1[j] = (short)f2bf(fmaxf(fmaf(ea, wee[8 + j], bee[8 + j]), 0.0f));
    }

    f32x4 acc[4] = {(f32x4)(0.f), (f32x4)(0.f), (f32x4)(0.f), (f32x4)(0.f)};
#pragma unroll
    for (int nt = 0; nt < 4; ++nt) {
      const unsigned short* bp = sB + (l15 + nt * 16) * 200 + l4 * 8;
      acc[nt] = __builtin_amdgcn_mfma_f32_16x16x32_bf16(a_s0, *(const bf16x8*)(bp),       acc[nt], 0, 0, 0);
      acc[nt] = __builtin_amdgcn_mfma_f32_16x16x32_bf16(a_s1, *(const bf16x8*)(bp + 32),  acc[nt], 0, 0, 0);
      acc[nt] = __builtin_amdgcn_mfma_f32_16x16x32_bf16(a_d0, *(const bf16x8*)(bp + 64),  acc[nt], 0, 0, 0);
      acc[nt] = __builtin_amdgcn_mfma_f32_16x16x32_bf16(a_d1, *(const bf16x8*)(bp + 96),  acc[nt], 0, 0, 0);
      acc[nt] = __builtin_amdgcn_mfma_f32_16x16x32_bf16(ae0,  *(const bf16x8*)(bp + 128), acc[nt], 0, 0, 0);
      acc[nt] = __builtin_amdgcn_mfma_f32_16x16x32_bf16(ae1,  *(const bf16x8*)(bp + 160), acc[nt], 0, 0, 0);
    }

    float p[4];
#pragma unroll
    for (int r = 0; r < 4; ++r) {
      float sum = 0.0f;
#pragma unroll
      for (int nt = 0; nt < 4; ++nt)
        sum = fmaf(fmaxf(acc[nt][r] + b1v[nt], 0.0f), w2v[nt], sum);
      p[r] = sum;
    }
#pragma unroll
    for (int m = 1; m <= 8; m <<= 1) {
#pragma unroll
      for (int r = 0; r < 4; ++r) p[r] += __shfl_xor(p[r], m);
    }
    if (l15 < 4) out[eBase + l4 * 4 + l15] = p[l15] + bias2;
  }
}

extern "C" void kernel_launch(void* const* d_in, const int* in_sizes, int n_in,
                              void* d_out, int out_size, void* d_ws, size_t ws_size,
                              hipStream_t stream) {
  const float* x     = (const float*)d_in[0];
  const int*   ei    = (const int*)d_in[1];
  const float* eattr = (const float*)d_in[2];
  const float* W_ne  = (const float*)d_in[3];
  const float* b_ne  = (const float*)d_in[4];
  const float* W_ee  = (const float*)d_in[5];
  const float* b_ee  = (const float*)d_in[6];
  const float* W_gcn = (const float*)d_in[7];
  const float* b_gcn = (const float*)d_in[8];
  const float* W1    = (const float*)d_in[9];
  const float* b1    = (const float*)d_in[10];
  const float* W2    = (const float*)d_in[11];
  const float* b2    = (const float*)d_in[12];
  float* out = (float*)d_out;

  char* ws = (char*)d_ws;
  unsigned short* htb = (unsigned short*)ws;                      // NN*H bf16 = 6.4 MB
  unsigned short* hgb = htb + (size_t)NN * H;                     // NN*H bf16 = 6.4 MB
  int*   cnt     = (int*)(hgb + (size_t)NN * H);                  // NN
  int*   rowptr  = cnt + NN;                                      // NN+1
  int*   cursor  = rowptr + NN + 1;                               // NN
  float* dinv    = (float*)(cursor + NN);                         // NN
  int*   csr_src = (int*)(dinv + NN);                             // NE
  unsigned short* W1t = (unsigned short*)(csr_src + NE);          // 64*200

  k_zero<<<(NN + 255) / 256, 256, 0, stream>>>(cnt);
  k_hist<<<NE / 256, 256, 0, stream>>>(ei, cnt);
  k_scan<<<1, 1024, 0, stream>>>(cnt, rowptr, cursor, dinv);
  k_prep_w1t<<<48, 256, 0, stream>>>(W1, W1t);
  k_node<<<NN / 4, 256, 0, stream>>>(x, W_ne, b_ne, W_gcn, dinv, htb);
  k_reorder<<<NE / 256, 256, 0, stream>>>(ei, cursor, csr_src);
  k_gather<<<NN / 4, 256, 0, stream>>>(rowptr, csr_src, htb, dinv, b_gcn, hgb);
  k_mlp_mfma<<<NE / 256, 256, 0, stream>>>(ei, eattr, hgb, W1t, W_ee, b_ee, b1, W2, b2, out);
}

// Round 4
// 220.205 us; speedup vs baseline: 1.6383x; 1.6383x over previous
//
#include <hip/hip_runtime.h>

#define NN 50000
#define NE 800000
#define H  64
#define SCAN_B 196  // ceil(NN/256); 196*256 = 50176

typedef __attribute__((ext_vector_type(8))) short bf16x8;
typedef __attribute__((ext_vector_type(4))) float f32x4;

__device__ __forceinline__ unsigned short f2bf(float f) {
  unsigned int u = __builtin_bit_cast(unsigned int, f);
  u += 0x7FFFu + ((u >> 16) & 1u);  // RNE
  return (unsigned short)(u >> 16);
}
__device__ __forceinline__ float bf2f(unsigned short u) {
  unsigned int v = ((unsigned int)u) << 16;
  return __builtin_bit_cast(float, v);
}

// ---------- count in-degree (dst) ----------
__global__ __launch_bounds__(256) void k_zero(int* __restrict__ cnt) {
  int i = blockIdx.x * 256 + threadIdx.x;
  if (i < NN) cnt[i] = 0;
}

__global__ __launch_bounds__(256) void k_hist(const int* __restrict__ ei,
                                              int* __restrict__ cnt) {
  int e = blockIdx.x * 256 + threadIdx.x;
  atomicAdd(&cnt[ei[NE + e]], 1);
}

// ---------- hierarchical exclusive scan ----------
__global__ __launch_bounds__(256) void k_scan_local(const int* __restrict__ cnt,
                                                    int* __restrict__ loc,
                                                    int* __restrict__ bsum) {
  __shared__ int sh[256];
  const int t = threadIdx.x;
  const int i = blockIdx.x * 256 + t;
  const int v = (i < NN) ? cnt[i] : 0;
  sh[t] = v;
  __syncthreads();
  int val = v;
#pragma unroll
  for (int off = 1; off < 256; off <<= 1) {
    int o = (t >= off) ? sh[t - off] : 0;
    __syncthreads();
    val += o;
    sh[t] = val;
    __syncthreads();
  }
  if (i < NN) loc[i] = val - v;  // exclusive
  if (t == 255) bsum[blockIdx.x] = val;
}

__global__ __launch_bounds__(256) void k_scan_bsum(const int* __restrict__ bsum,
                                                   int* __restrict__ boff) {
  __shared__ int sh[256];
  const int t = threadIdx.x;
  const int v = (t < SCAN_B) ? bsum[t] : 0;
  sh[t] = v;
  __syncthreads();
  int val = v;
#pragma unroll
  for (int off = 1; off < 256; off <<= 1) {
    int o = (t >= off) ? sh[t - off] : 0;
    __syncthreads();
    val += o;
    sh[t] = val;
    __syncthreads();
  }
  if (t < SCAN_B) boff[t] = val - v;  // exclusive
}

__global__ __launch_bounds__(256) void k_scan_add(const int* __restrict__ loc,
                                                  const int* __restrict__ boff,
                                                  const int* __restrict__ cnt,
                                                  int* __restrict__ rowptr,
                                                  int* __restrict__ cursor,
                                                  float* __restrict__ dinv) {
  const int i = blockIdx.x * 256 + threadIdx.x;
  if (i < NN) {
    const int r = loc[i] + boff[blockIdx.x];
    rowptr[i] = r;
    cursor[i] = r;
    dinv[i] = rsqrtf((float)(cnt[i] + 1));  // +1 self-loop
  }
  if (i == 0) rowptr[NN] = NE;
}

// ---------- node encoder + h0@W_gcn; htb = bf16(ht * dinv[n]) ----------
__global__ __launch_bounds__(256) void k_node(
    const float* __restrict__ x, const float* __restrict__ W_ne,
    const float* __restrict__ b_ne, const float* __restrict__ W_gcn,
    const float* __restrict__ dinv, unsigned short* __restrict__ htb) {
  __shared__ float sh[4][H];
  const int lane = threadIdx.x & 63;
  const int wv   = threadIdx.x >> 6;
  const int n    = blockIdx.x * 4 + wv;

  float acc = b_ne[lane];
#pragma unroll
  for (int k = 0; k < 5; ++k) acc = fmaf(x[n * 5 + k], W_ne[k * H + lane], acc);
  acc = fmaxf(acc, 0.0f);
  sh[wv][lane] = acc;
  __syncthreads();

  float hv = 0.0f;
#pragma unroll 8
  for (int k = 0; k < H; ++k) hv = fmaf(sh[wv][k], W_gcn[k * H + lane], hv);

  htb[(size_t)n * H + lane] = f2bf(hv * dinv[n]);
}

// ---------- reorder: csr_src grouped by dst ----------
__global__ __launch_bounds__(256) void k_reorder(const int* __restrict__ ei,
                                                 int* __restrict__ cursor,
                                                 int* __restrict__ csr_src) {
  int e = blockIdx.x * 256 + threadIdx.x;
  int s = ei[e], d = ei[NE + e];
  int pos = atomicAdd(&cursor[d], 1);
  csr_src[pos] = s;
}

// ---------- gather: hgb[d] = bf16(dinv[d]*(htb[d] + sum htb[src]) + b_gcn) ----------
__global__ __launch_bounds__(256) void k_gather(
    const int* __restrict__ rowptr, const int* __restrict__ csr_src,
    const unsigned short* __restrict__ htb, const float* __restrict__ dinv,
    const float* __restrict__ b_gcn, unsigned short* __restrict__ hgb) {
  const int lane = threadIdx.x & 63;
  const int wv   = threadIdx.x >> 6;
  const int n    = blockIdx.x * 4 + wv;  // NN % 4 == 0
  const int beg = rowptr[n], end = rowptr[n + 1];

  float sum = bf2f(htb[(size_t)n * H + lane]);  // self-loop term
  int i = beg;
#pragma unroll 1
  for (; i + 4 <= end; i += 4) {
    const int s0 = csr_src[i], s1 = csr_src[i + 1];
    const int s2 = csr_src[i + 2], s3 = csr_src[i + 3];
    const float v0 = bf2f(htb[(size_t)s0 * H + lane]);
    const float v1 = bf2f(htb[(size_t)s1 * H + lane]);
    const float v2 = bf2f(htb[(size_t)s2 * H + lane]);
    const float v3 = bf2f(htb[(size_t)s3 * H + lane]);
    sum += (v0 + v1) + (v2 + v3);
  }
#pragma unroll 1
  for (; i < end; ++i) sum += bf2f(htb[(size_t)csr_src[i] * H + lane]);

  hgb[(size_t)n * H + lane] = f2bf(fmaf(dinv[n], sum, b_gcn[lane]));
}

// ---------- prep: W1 (f32 [192][64]) -> W1t (bf16 [64][200], padded) ----------
__global__ __launch_bounds__(256) void k_prep_w1t(const float* __restrict__ W1,
                                                  unsigned short* __restrict__ W1t) {
  const int t = blockIdx.x * 256 + threadIdx.x;  // 48*256 = 12288 = 192*64
  const int n = t / 192, k = t % 192;
  W1t[n * 200 + k] = f2bf(W1[k * H + n]);
}

// ---------- MFMA edge MLP ----------
__global__ __launch_bounds__(256) void k_mlp_mfma(
    const int* __restrict__ ei, const float* __restrict__ eattr,
    const unsigned short* __restrict__ hgb, const unsigned short* __restrict__ W1t,
    const float* __restrict__ W_ee, const float* __restrict__ b_ee,
    const float* __restrict__ b1, const float* __restrict__ W2,
    const float* __restrict__ b2, float* __restrict__ out) {
  __shared__ unsigned short sB[64 * 200];  // 25.6 KB, [n][k] padded

  {  // cooperative LDS fill: 12800 ushort = 6400 dwords = 25/thread
    const unsigned int* g = (const unsigned int*)W1t;
    unsigned int* s = (unsigned int*)sB;
#pragma unroll
    for (int i = 0; i < 25; ++i) s[threadIdx.x + 256 * i] = g[threadIdx.x + 256 * i];
  }
  __syncthreads();

  const int lane = threadIdx.x & 63;
  const int wv   = threadIdx.x >> 6;
  const int l15  = lane & 15;
  const int l4   = lane >> 4;

  float wee[16], bee[16], w2v[4], b1v[4];
#pragma unroll
  for (int j = 0; j < 8; ++j) {
    wee[j]     = W_ee[l4 * 8 + j];      bee[j]     = b_ee[l4 * 8 + j];
    wee[8 + j] = W_ee[32 + l4 * 8 + j]; bee[8 + j] = b_ee[32 + l4 * 8 + j];
  }
#pragma unroll
  for (int nt = 0; nt < 4; ++nt) {
    w2v[nt] = W2[l15 + 16 * nt];
    b1v[nt] = b1[l15 + 16 * nt];
  }
  const float bias2 = b2[0];

#pragma unroll 1
  for (int t = 0; t < 4; ++t) {
    const int eBase = (blockIdx.x * 16 + wv * 4 + t) * 16;
    const int el = eBase + l15;
    const int s = ei[el], d = ei[NE + el];
    const float ea = eattr[el];

    const bf16x8 a_s0 = *(const bf16x8*)(hgb + (size_t)s * H + l4 * 8);
    const bf16x8 a_s1 = *(const bf16x8*)(hgb + (size_t)s * H + 32 + l4 * 8);
    const bf16x8 a_d0 = *(const bf16x8*)(hgb + (size_t)d * H + l4 * 8);
    const bf16x8 a_d1 = *(const bf16x8*)(hgb + (size_t)d * H + 32 + l4 * 8);

    bf16x8 ae0, ae1;
#pragma unroll
    for (int j = 0; j < 8; ++j) {
      ae0[j] = (short)f2bf(fmaxf(fmaf(ea, wee[j], bee[j]), 0.0f));
      ae1[j] = (short)f2bf(fmaxf(fmaf(ea, wee[8 + j], bee[8 + j]), 0.0f));
    }

    f32x4 acc[4] = {(f32x4)(0.f), (f32x4)(0.f), (f32x4)(0.f), (f32x4)(0.f)};
#pragma unroll
    for (int nt = 0; nt < 4; ++nt) {
      const unsigned short* bp = sB + (l15 + nt * 16) * 200 + l4 * 8;
      acc[nt] = __builtin_amdgcn_mfma_f32_16x16x32_bf16(a_s0, *(const bf16x8*)(bp),       acc[nt], 0, 0, 0);
      acc[nt] = __builtin_amdgcn_mfma_f32_16x16x32_bf16(a_s1, *(const bf16x8*)(bp + 32),  acc[nt], 0, 0, 0);
      acc[nt] = __builtin_amdgcn_mfma_f32_16x16x32_bf16(a_d0, *(const bf16x8*)(bp + 64),  acc[nt], 0, 0, 0);
      acc[nt] = __builtin_amdgcn_mfma_f32_16x16x32_bf16(a_d1, *(const bf16x8*)(bp + 96),  acc[nt], 0, 0, 0);
      acc[nt] = __builtin_amdgcn_mfma_f32_16x16x32_bf16(ae0,  *(const bf16x8*)(bp + 128), acc[nt], 0, 0, 0);
      acc[nt] = __builtin_amdgcn_mfma_f32_16x16x32_bf16(ae1,  *(const bf16x8*)(bp + 160), acc[nt], 0, 0, 0);
    }

    float p[4];
#pragma unroll
    for (int r = 0; r < 4; ++r) {
      float sum = 0.0f;
#pragma unroll
      for (int nt = 0; nt < 4; ++nt)
        sum = fmaf(fmaxf(acc[nt][r] + b1v[nt], 0.0f), w2v[nt], sum);
      p[r] = sum;
    }
#pragma unroll
    for (int m = 1; m <= 8; m <<= 1) {
#pragma unroll
      for (int r = 0; r < 4; ++r) p[r] += __shfl_xor(p[r], m);
    }
    if (l15 < 4) out[eBase + l4 * 4 + l15] = p[l15] + bias2;
  }
}

extern "C" void kernel_launch(void* const* d_in, const int* in_sizes, int n_in,
                              void* d_out, int out_size, void* d_ws, size_t ws_size,
                              hipStream_t stream) {
  const float* x     = (const float*)d_in[0];
  const int*   ei    = (const int*)d_in[1];
  const float* eattr = (const float*)d_in[2];
  const float* W_ne  = (const float*)d_in[3];
  const float* b_ne  = (const float*)d_in[4];
  const float* W_ee  = (const float*)d_in[5];
  const float* b_ee  = (const float*)d_in[6];
  const float* W_gcn = (const float*)d_in[7];
  const float* b_gcn = (const float*)d_in[8];
  const float* W1    = (const float*)d_in[9];
  const float* b1    = (const float*)d_in[10];
  const float* W2    = (const float*)d_in[11];
  const float* b2    = (const float*)d_in[12];
  float* out = (float*)d_out;

  char* ws = (char*)d_ws;
  unsigned short* htb = (unsigned short*)ws;                      // NN*H bf16
  unsigned short* hgb = htb + (size_t)NN * H;                     // NN*H bf16
  int*   cnt     = (int*)(hgb + (size_t)NN * H);                  // NN
  int*   rowptr  = cnt + NN;                                      // NN+1
  int*   cursor  = rowptr + NN + 1;                               // NN
  float* dinv    = (float*)(cursor + NN);                         // NN
  int*   csr_src = (int*)(dinv + NN);                             // NE
  unsigned short* W1t = (unsigned short*)(csr_src + NE);          // 64*200
  int*   loc     = (int*)(W1t + 64 * 200);                        // NN
  int*   bsum    = loc + NN;                                      // SCAN_B
  int*   boff    = bsum + SCAN_B;                                 // SCAN_B

  k_zero<<<SCAN_B, 256, 0, stream>>>(cnt);
  k_hist<<<NE / 256, 256, 0, stream>>>(ei, cnt);
  k_scan_local<<<SCAN_B, 256, 0, stream>>>(cnt, loc, bsum);
  k_scan_bsum<<<1, 256, 0, stream>>>(bsum, boff);
  k_scan_add<<<SCAN_B, 256, 0, stream>>>(loc, boff, cnt, rowptr, cursor, dinv);
  k_prep_w1t<<<48, 256, 0, stream>>>(W1, W1t);
  k_node<<<NN / 4, 256, 0, stream>>>(x, W_ne, b_ne, W_gcn, dinv, htb);
  k_reorder<<<NE / 256, 256, 0, stream>>>(ei, cursor, csr_src);
  k_gather<<<NN / 4, 256, 0, stream>>>(rowptr, csr_src, htb, dinv, b_gcn, hgb);
  k_mlp_mfma<<<NE / 256, 256, 0, stream>>>(ei, eattr, hgb, W1t, W_ee, b_ee, b1, W2, b2, out);
}